// Round 15
// baseline (455.671 us; speedup 1.0000x reference)
//
#include <hip/hip_runtime.h>
#include <stdint.h>

typedef int v4i __attribute__((ext_vector_type(4)));

#define M_DIM 8192   // B*S = 2*4096
#define N_DIM 8192   // OUT
#define K_DIM 2048   // IN
#define RISKY_TAU 1e-4f
#define BUCKET_CAP 1024
#define BSLOT 16384  // LDS ring slot: B[256][64] only (A goes global->VGPR)

// async global->LDS, 16B per lane (dest = wave-uniform base + lane*16)
#define ASYNC16(g, l) __builtin_amdgcn_global_load_lds(                        \
    (const __attribute__((address_space(1))) void*)(uintptr_t)(g),             \
    (__attribute__((address_space(3))) void*)(uint32_t)(uintptr_t)(l), 16, 0, 0)

// ---------------- 1) numpy-pairwise f32 sum of |w| ----------------
__global__ __launch_bounds__(256) void abssum_stage1(const float* __restrict__ w,
                                                     float* __restrict__ s1) {
  int b = blockIdx.x * 256 + threadIdx.x;  // 131072 leaf blocks of 128
  const float* p = w + (size_t)b * 128;
  float r[8];
#pragma unroll
  for (int j = 0; j < 8; j++) r[j] = fabsf(p[j]);
  for (int i = 8; i < 128; i += 8) {
#pragma unroll
    for (int j = 0; j < 8; j++) r[j] += fabsf(p[i + j]);
  }
  s1[b] = ((r[0] + r[1]) + (r[2] + r[3])) + ((r[4] + r[5]) + (r[6] + r[7]));
}

__global__ __launch_bounds__(256) void abssum_stage2(const float* __restrict__ s1,
                                                     float* __restrict__ s2) {
  int t = blockIdx.x * 256 + threadIdx.x;  // 4096 threads
  float v[32];
#pragma unroll
  for (int i = 0; i < 32; i++) v[i] = s1[t * 32 + i];
#pragma unroll
  for (int s = 1; s < 32; s *= 2) {
#pragma unroll
    for (int i = 0; i < 32; i += 2 * s) v[i] += v[i + s];
  }
  s2[t] = v[0];
}

__global__ __launch_bounds__(256) void gamma_stage3(const float* __restrict__ s2,
                                                    float* __restrict__ gp) {
  int t = threadIdx.x;  // 256 threads, one block
  float v[16];
#pragma unroll
  for (int i = 0; i < 16; i++) v[i] = s2[t * 16 + i];
#pragma unroll
  for (int s = 1; s < 16; s *= 2) {
#pragma unroll
    for (int i = 0; i < 16; i += 2 * s) v[i] += v[i + s];
  }
  __shared__ float sm[256];
  sm[t] = v[0];
  for (int s = 1; s < 256; s *= 2) {
    __syncthreads();
    if ((t & (2 * s - 1)) == 0) sm[t] += sm[t + s];
  }
  __syncthreads();
  if (t == 0) {
    float g = sm[0] * 0x1p-24f;  // /(8192*2048), exact pow2 scale
    gp[0] = fmaxf(g, 1e-5f);
  }
}

__global__ void zero_counts(int* __restrict__ counts) {
  counts[threadIdx.x] = 0;
}

// ---------------- 2) ternary weight quant + risky-midpoint detection ----------------
__global__ __launch_bounds__(256) void wq_kernel(const float4* __restrict__ w4,
                                                 const float* __restrict__ gp,
                                                 int* __restrict__ wq,
                                                 int* __restrict__ counts,
                                                 int* __restrict__ buckets) {
  int i = blockIdx.x * 256 + threadIdx.x;
  float g = gp[0];
  float4 v = w4[i];
  float e[4] = {v.x, v.y, v.z, v.w};
  int q[4];
#pragma unroll
  for (int c = 0; c < 4; c++) {
    q[c] = (int)rintf(fminf(fmaxf(e[c] / g, -1.0f), 1.0f));
    float t = fabsf(e[c]) / g;
    if (fabsf(t - 0.5f) < RISKY_TAU) {
      int flat = i * 4 + c;
      int n = flat >> 11;          // weight row (output col)
      int k = flat & 2047;
      int sgn_neg = (e[c] < 0.0f) ? 1 : 0;
      int sbit = (q[c] == 0) ? sgn_neg : (1 - sgn_neg);
      int b = n >> 7;
      int idx = atomicAdd(&counts[b], 1);
      if (idx < BUCKET_CAP)
        buckets[b * BUCKET_CAP + idx] = k | (n << 11) | (sbit << 24);
    }
  }
  wq[i] = (q[0] & 0xFF) | ((q[1] & 0xFF) << 8) | ((q[2] & 0xFF) << 16) | ((q[3] & 0xFF) << 24);
}

// ---------------- 3) fused LayerNorm + absmax int8 quant (one block per row) ----------------
__global__ __launch_bounds__(256) void lnq_kernel(const float* __restrict__ x,
                                                  const float* __restrict__ gp,
                                                  int8_t* __restrict__ xq,
                                                  float* __restrict__ scales) {
  const int row = blockIdx.x;
  const int t = threadIdx.x;
  const float4* xr = (const float4*)(x + (size_t)row * K_DIM);
  float4 a = xr[t];
  float4 b = xr[t + 256];
  double v[8] = {a.x, a.y, a.z, a.w, b.x, b.y, b.z, b.w};
  double s = 0.0, ss = 0.0;
#pragma unroll
  for (int i = 0; i < 8; i++) { s += v[i]; ss += v[i] * v[i]; }
  __shared__ double sm1[256], sm2[256];
  sm1[t] = s; sm2[t] = ss;
  __syncthreads();
  for (int off = 128; off > 0; off >>= 1) {
    if (t < off) { sm1[t] += sm1[t + off]; sm2[t] += sm2[t + off]; }
    __syncthreads();
  }
  double mu = sm1[0] * (1.0 / 2048.0);
  double var = sm2[0] * (1.0 / 2048.0) - mu * mu;  // biased variance
  double inv = 1.0 / sqrt(var + 1e-5);
  __syncthreads();
  double mx = 0.0;
#pragma unroll
  for (int i = 0; i < 8; i++) {
    v[i] = (v[i] - mu) * inv;
    double av = fabs(v[i]);
    if (av > mx) mx = av;
  }
  sm1[t] = mx;
  __syncthreads();
  for (int off = 128; off > 0; off >>= 1) {
    if (t < off) sm1[t] = fmax(sm1[t], sm1[t + off]);
    __syncthreads();
  }
  double eta = fmax(sm1[0], 1e-5);
  double r = 127.0 / eta;
  int q[8];
#pragma unroll
  for (int i = 0; i < 8; i++) {
    double qq = rint(v[i] * r);  // round-half-even, then clip
    qq = fmin(fmax(qq, -128.0), 127.0);
    q[i] = (int)qq;
  }
  int p0 = (q[0] & 0xFF) | ((q[1] & 0xFF) << 8) | ((q[2] & 0xFF) << 16) | ((q[3] & 0xFF) << 24);
  int p1 = (q[4] & 0xFF) | ((q[5] & 0xFF) << 8) | ((q[6] & 0xFF) << 16) | ((q[7] & 0xFF) << 24);
  int* orow = (int*)(xq + (size_t)row * K_DIM);
  orow[t] = p0;
  orow[t + 256] = p1;
  if (t == 0) scales[row] = (float)((double)gp[0] * eta * (1.0 / 127.0));
}

// ---------------- 4) int8 MFMA GEMM: 256x256, A global->VGPR, B ring-3 LDS --------------
// LDS-offload experiment: A fragments are loaded straight to registers (prefetched one
// K-step ahead, parity-swapped aA/aB sets, static indexing), B keeps the proven r12 path
// (ring-3 16KB slots, (r>>1)&3 swizzle, counted vmcnt). LDS traffic/step: 256KB -> 48KB.
// vmcnt(2) bookkeeping per step (issue order-robust): outstanding before wait =
// {2x B(t+1) oldest} + {8x A(t+1), 2x B(t+2) this step}; vmcnt(2) always completes
// B(t+1); A-reg completion is additionally covered by compiler auto-waits before use.
__global__ __launch_bounds__(512, 2) void gemm_i8_kernel(const int8_t* __restrict__ A,
                                                         const int8_t* __restrict__ B,
                                                         const float* __restrict__ scales,
                                                         const float* __restrict__ bias,
                                                         const int* __restrict__ counts,
                                                         const int* __restrict__ buckets,
                                                         float* __restrict__ C) {
  __shared__ alignas(16) int8_t lds[3 * BSLOT];  // 48 KiB (B only)
  const int tid = threadIdx.x;
  const int wave = tid >> 6;   // 0..7
  const int lane = tid & 63;

  // XCD slab swizzle: 1024 blocks, xcd = b&7 owns tile rows [4*xcd, 4*xcd+4), col-major
  const int b = blockIdx.x;
  const int tr = (b & 7) * 4 + ((b >> 3) & 3);
  const int tc = b >> 5;
  const int brow = tr * 256;
  const int bcol = tc * 256;

  // B staging: 16 chunks of 1KB (16 rows x 64B); wave w stages chunks {2w,2w+1}.
  const int chunkr = lane >> 2;
  const int sl = lane & 3;
  const int8_t* gB[2];
  int dB[2];
#pragma unroll
  for (int c = 0; c < 2; c++) {
    int ch = wave * 2 + c;
    int r = ch * 16 + chunkr;
    int scol = ((sl ^ ((r >> 1) & 3)) << 4);
    gB[c] = B + (size_t)(bcol + r) * K_DIM + scol;
    dB[c] = ch * 1024;           // wave-uniform LDS base (+lane*16 by HW)
  }

  // B fragment read offsets (swizzled), slot-relative
  const int wr = wave >> 2;    // 0..1  (M half)
  const int wc = wave & 3;     // 0..3  (N quarter)
  const int ks = lane >> 4;    // k-slot 0..3
  int boff[4];
#pragma unroll
  for (int n = 0; n < 4; n++) {
    int r = wc * 64 + n * 16 + (lane & 15);
    boff[n] = r * 64 + ((ks ^ ((r >> 1) & 3)) << 4);
  }

  // A direct-load base: row = brow + wr*128 + m*16 + (lane&15), 16B chunk = ks
  const int8_t* gAr = A + (size_t)(brow + wr * 128 + (lane & 15)) * K_DIM + ks * 16;

  v4i acc[8][4];
  const v4i vzero = {0, 0, 0, 0};
#pragma unroll
  for (int m = 0; m < 8; m++)
#pragma unroll
    for (int n = 0; n < 4; n++) acc[m][n] = vzero;

  v4i aA[8], aB[8], bf[4];

  // prologue: B(0)->slot0 ; A(0)->aA ; B(1)->slot1   (B0 oldest -> vmcnt(2) covers it)
#pragma unroll
  for (int c = 0; c < 2; c++) ASYNC16(gB[c], lds + dB[c]);
#pragma unroll
  for (int m = 0; m < 8; m++) aA[m] = *(const v4i*)(gAr + (size_t)m * 16 * K_DIM);
#pragma unroll
  for (int c = 0; c < 2; c++) ASYNC16(gB[c] + 64, lds + BSLOT + dB[c]);
  asm volatile("s_waitcnt vmcnt(2)" ::: "memory");
  __builtin_amdgcn_s_barrier();

  int rbase = 0;         // read slot base
  int sbase = 2 * BSLOT; // stage slot base

#define GEMM_STEP(T, USE, LOADARR)                                             \
  {                                                                            \
    if ((T) < 31) {                                                            \
      const size_t ka = (size_t)((T) + 1) * 64;                                \
      _Pragma("unroll") for (int m = 0; m < 8; m++)                            \
        LOADARR[m] = *(const v4i*)(gAr + (size_t)m * 16 * K_DIM + ka);         \
    }                                                                          \
    if ((T) < 30) {                                                            \
      const int kb = ((T) + 2) * 64;                                           \
      ASYNC16(gB[0] + kb, lds + sbase + dB[0]);                                \
      ASYNC16(gB[1] + kb, lds + sbase + dB[1]);                                \
    }                                                                          \
    _Pragma("unroll") for (int n = 0; n < 4; n++)                              \
      bf[n] = *(const v4i*)(lds + rbase + boff[n]);                            \
    __builtin_amdgcn_s_setprio(1);                                             \
    _Pragma("unroll") for (int m = 0; m < 8; m++)                              \
      _Pragma("unroll") for (int n = 0; n < 4; n++)                            \
        acc[m][n] = __builtin_amdgcn_mfma_i32_16x16x64_i8(USE[m], bf[n], acc[m][n], 0, 0, 0); \
    __builtin_amdgcn_s_setprio(0);                                             \
    if ((T) < 30) asm volatile("s_waitcnt vmcnt(2)" ::: "memory");             \
    else          asm volatile("s_waitcnt vmcnt(0)" ::: "memory");             \
    __builtin_amdgcn_s_barrier();                                              \
    rbase = (rbase == 2 * BSLOT) ? 0 : rbase + BSLOT;                          \
    sbase = (sbase == 2 * BSLOT) ? 0 : sbase + BSLOT;                          \
  }

  for (int tt = 0; tt < 16; ++tt) {
    GEMM_STEP(tt * 2, aA, aB)
    GEMM_STEP(tt * 2 + 1, aB, aA)
  }
#undef GEMM_STEP

  // double accumulators (midpoint = odd integer), then apply risky corrections
#pragma unroll
  for (int m = 0; m < 8; m++)
#pragma unroll
    for (int n = 0; n < 4; n++) acc[m][n] = acc[m][n] + acc[m][n];

  const int crow0 = brow + wr * 128;
  const int ccol0 = bcol + wc * 64;

#define CORR(J)                                                                \
  {                                                                            \
    _Pragma("unroll") for (int m = 0; m < 8; m++) {                            \
      _Pragma("unroll") for (int r = 0; r < 4; r++) {                          \
        int grow = crow0 + m * 16 + ((lane >> 4) << 2) + r;                    \
        int xv = (int)A[(size_t)grow * K_DIM + k];                             \
        acc[m][J][r] += sv * xv;                                               \
      }                                                                        \
    }                                                                          \
  }

  {
    int bkt = (bcol + wc * 64) >> 7;  // 128-col bucket containing this wave's 64 cols
    int cnt = counts[bkt];
    if (cnt > BUCKET_CAP) cnt = BUCKET_CAP;
    const int* bk = buckets + bkt * BUCKET_CAP;
    for (int e = 0; e < cnt; ++e) {
      int word = bk[e];
      int k = word & 2047;
      int nc = (word >> 11) & 8191;
      int sv = ((word >> 24) & 1) ? -1 : 1;
      if (((nc >> 6) & 1) == (wc & 1) && (nc & 15) == (lane & 15)) {
        int j = (nc >> 4) & 3;
        switch (j) {
          case 0: CORR(0); break;
          case 1: CORR(1); break;
          case 2: CORR(2); break;
          case 3: CORR(3); break;
        }
      }
    }
  }
#undef CORR

  // epilogue: C[m][n] = (2*acc_corrected) * (scale_m/2) + bias[n]  (normal cached stores)
#pragma unroll
  for (int m = 0; m < 8; m++) {
#pragma unroll
    for (int r = 0; r < 4; r++) {
      int grow = crow0 + m * 16 + ((lane >> 4) << 2) + r;
      float sc = scales[grow] * 0.5f;
      float* crow = C + (size_t)grow * N_DIM;
#pragma unroll
      for (int n = 0; n < 4; n++) {
        int gcol = ccol0 + n * 16 + (lane & 15);
        crow[gcol] = (float)acc[m][n][r] * sc + bias[gcol];
      }
    }
  }
}

extern "C" void kernel_launch(void* const* d_in, const int* in_sizes, int n_in,
                              void* d_out, int out_size, void* d_ws, size_t ws_size,
                              hipStream_t stream) {
  const float* x = (const float*)d_in[0];
  const float* w = (const float*)d_in[1];
  const float* bias = (const float*)d_in[2];
  float* out = (float*)d_out;

  char* ws = (char*)d_ws;
  float* s1 = (float*)(ws);                          // 512 KiB
  float* s2 = (float*)(ws + 0x100000);               // 16 KiB
  float* gamma_f = (float*)(ws + 0x110000);          // 4 B
  float* scales = (float*)(ws + 0x120000);           // 32 KiB
  int* counts = (int*)(ws + 0x130000);               // 64 * 4 B
  int* buckets = (int*)(ws + 0x131000);              // 256 KiB
  int8_t* Aq = (int8_t*)(ws + 0x200000);                             // 16 MiB
  int8_t* Wq = (int8_t*)(ws + 0x200000 + (size_t)M_DIM * K_DIM);     // 16 MiB

  abssum_stage1<<<512, 256, 0, stream>>>(w, s1);
  abssum_stage2<<<16, 256, 0, stream>>>(s1, s2);
  gamma_stage3<<<1, 256, 0, stream>>>(s2, gamma_f);
  zero_counts<<<1, 64, 0, stream>>>(counts);
  wq_kernel<<<(N_DIM * K_DIM / 4 + 255) / 256, 256, 0, stream>>>(
      (const float4*)w, gamma_f, (int*)Wq, counts, buckets);
  lnq_kernel<<<M_DIM, 256, 0, stream>>>(x, gamma_f, Aq, scales);
  gemm_i8_kernel<<<1024, 512, 0, stream>>>(Aq, Wq, scales, bias, counts, buckets, out);
}

// Round 16
// 309.005 us; speedup vs baseline: 1.4746x; 1.4746x over previous
//
#include <hip/hip_runtime.h>
#include <stdint.h>

typedef int v4i __attribute__((ext_vector_type(4)));

#define M_DIM 8192   // B*S = 2*4096
#define N_DIM 8192   // OUT
#define K_DIM 2048   // IN
#define RISKY_TAU 1e-4f
#define BUCKET_CAP 1024
#define SLOT 16384   // LDS ring slot: A[128][64] 8KB + B[128][64] 8KB

// async global->LDS, 16B per lane (dest = wave-uniform base + lane*16)
#define ASYNC16(g, l) __builtin_amdgcn_global_load_lds(                        \
    (const __attribute__((address_space(1))) void*)(uintptr_t)(g),             \
    (__attribute__((address_space(3))) void*)(uint32_t)(uintptr_t)(l), 16, 0, 0)

// ---------------- 1) numpy-pairwise f32 sum of |w| ----------------
__global__ __launch_bounds__(256) void abssum_stage1(const float* __restrict__ w,
                                                     float* __restrict__ s1) {
  int b = blockIdx.x * 256 + threadIdx.x;  // 131072 leaf blocks of 128
  const float* p = w + (size_t)b * 128;
  float r[8];
#pragma unroll
  for (int j = 0; j < 8; j++) r[j] = fabsf(p[j]);
  for (int i = 8; i < 128; i += 8) {
#pragma unroll
    for (int j = 0; j < 8; j++) r[j] += fabsf(p[i + j]);
  }
  s1[b] = ((r[0] + r[1]) + (r[2] + r[3])) + ((r[4] + r[5]) + (r[6] + r[7]));
}

__global__ __launch_bounds__(256) void abssum_stage2(const float* __restrict__ s1,
                                                     float* __restrict__ s2) {
  int t = blockIdx.x * 256 + threadIdx.x;  // 4096 threads
  float v[32];
#pragma unroll
  for (int i = 0; i < 32; i++) v[i] = s1[t * 32 + i];
#pragma unroll
  for (int s = 1; s < 32; s *= 2) {
#pragma unroll
    for (int i = 0; i < 32; i += 2 * s) v[i] += v[i + s];
  }
  s2[t] = v[0];
}

__global__ __launch_bounds__(256) void gamma_stage3(const float* __restrict__ s2,
                                                    float* __restrict__ gp,
                                                    int* __restrict__ counts) {
  int t = threadIdx.x;  // 256 threads, one block
  if (t < 64) counts[t] = 0;  // fold zero_counts launch in here
  float v[16];
#pragma unroll
  for (int i = 0; i < 16; i++) v[i] = s2[t * 16 + i];
#pragma unroll
  for (int s = 1; s < 16; s *= 2) {
#pragma unroll
    for (int i = 0; i < 16; i += 2 * s) v[i] += v[i + s];
  }
  __shared__ float sm[256];
  sm[t] = v[0];
  for (int s = 1; s < 256; s *= 2) {
    __syncthreads();
    if ((t & (2 * s - 1)) == 0) sm[t] += sm[t + s];
  }
  __syncthreads();
  if (t == 0) {
    float g = sm[0] * 0x1p-24f;  // /(8192*2048), exact pow2 scale
    gp[0] = fmaxf(g, 1e-5f);
  }
}

// ---------------- 2) ternary weight quant + risky-midpoint detection ----------------
__global__ __launch_bounds__(256) void wq_kernel(const float4* __restrict__ w4,
                                                 const float* __restrict__ gp,
                                                 int* __restrict__ wq,
                                                 int* __restrict__ counts,
                                                 int* __restrict__ buckets) {
  int i = blockIdx.x * 256 + threadIdx.x;
  float g = gp[0];
  float4 v = w4[i];
  float e[4] = {v.x, v.y, v.z, v.w};
  int q[4];
#pragma unroll
  for (int c = 0; c < 4; c++) {
    q[c] = (int)rintf(fminf(fmaxf(e[c] / g, -1.0f), 1.0f));
    float t = fabsf(e[c]) / g;
    if (fabsf(t - 0.5f) < RISKY_TAU) {
      int flat = i * 4 + c;
      int n = flat >> 11;          // weight row (output col)
      int k = flat & 2047;
      int sgn_neg = (e[c] < 0.0f) ? 1 : 0;
      int sbit = (q[c] == 0) ? sgn_neg : (1 - sgn_neg);
      int b = n >> 7;
      int idx = atomicAdd(&counts[b], 1);
      if (idx < BUCKET_CAP)
        buckets[b * BUCKET_CAP + idx] = k | (n << 11) | (sbit << 24);
    }
  }
  wq[i] = (q[0] & 0xFF) | ((q[1] & 0xFF) << 8) | ((q[2] & 0xFF) << 16) | ((q[3] & 0xFF) << 24);
}

// ---------------- 3) fused LayerNorm + absmax int8 quant (one block per row) ----------------
__global__ __launch_bounds__(256) void lnq_kernel(const float* __restrict__ x,
                                                  const float* __restrict__ gp,
                                                  int8_t* __restrict__ xq,
                                                  float* __restrict__ scales) {
  const int row = blockIdx.x;
  const int t = threadIdx.x;
  const float4* xr = (const float4*)(x + (size_t)row * K_DIM);
  float4 a = xr[t];
  float4 b = xr[t + 256];
  double v[8] = {a.x, a.y, a.z, a.w, b.x, b.y, b.z, b.w};
  double s = 0.0, ss = 0.0;
#pragma unroll
  for (int i = 0; i < 8; i++) { s += v[i]; ss += v[i] * v[i]; }
  __shared__ double sm1[256], sm2[256];
  sm1[t] = s; sm2[t] = ss;
  __syncthreads();
  for (int off = 128; off > 0; off >>= 1) {
    if (t < off) { sm1[t] += sm1[t + off]; sm2[t] += sm2[t + off]; }
    __syncthreads();
  }
  double mu = sm1[0] * (1.0 / 2048.0);
  double var = sm2[0] * (1.0 / 2048.0) - mu * mu;  // biased variance
  double inv = 1.0 / sqrt(var + 1e-5);
  __syncthreads();
  double mx = 0.0;
#pragma unroll
  for (int i = 0; i < 8; i++) {
    v[i] = (v[i] - mu) * inv;
    double av = fabs(v[i]);
    if (av > mx) mx = av;
  }
  sm1[t] = mx;
  __syncthreads();
  for (int off = 128; off > 0; off >>= 1) {
    if (t < off) sm1[t] = fmax(sm1[t], sm1[t + off]);
    __syncthreads();
  }
  double eta = fmax(sm1[0], 1e-5);
  double r = 127.0 / eta;
  int q[8];
#pragma unroll
  for (int i = 0; i < 8; i++) {
    double qq = rint(v[i] * r);  // round-half-even, then clip
    qq = fmin(fmax(qq, -128.0), 127.0);
    q[i] = (int)qq;
  }
  int p0 = (q[0] & 0xFF) | ((q[1] & 0xFF) << 8) | ((q[2] & 0xFF) << 16) | ((q[3] & 0xFF) << 24);
  int p1 = (q[4] & 0xFF) | ((q[5] & 0xFF) << 8) | ((q[6] & 0xFF) << 16) | ((q[7] & 0xFF) << 24);
  int* orow = (int*)(xq + (size_t)row * K_DIM);
  orow[t] = p0;
  orow[t + 256] = p1;
  if (t == 0) scales[row] = (float)((double)gp[0] * eta * (1.0 / 127.0));
}

// ---------------- 4) int8 MFMA GEMM: 128x128, 4 waves, ring-3, counted vmcnt, 3 blk/CU --
// The untested combination: r8's multi-block residency (48KB LDS -> 3 blocks/CU, 12
// waves/CU cross-block TLP) x r12's counted-vmcnt ring-3 schedule (never drain to 0
// in-loop). Per-block logic identical to the proven r8 fragments + r12 sync. Slab
// swizzle: xcd=b&7 owns 8 tile-rows, col-major within (per-XCD window ~2MB A + ~3MB B).
__global__ __launch_bounds__(256) void gemm_i8_kernel(const int8_t* __restrict__ A,
                                                      const int8_t* __restrict__ B,
                                                      const float* __restrict__ scales,
                                                      const float* __restrict__ bias,
                                                      const int* __restrict__ counts,
                                                      const int* __restrict__ buckets,
                                                      float* __restrict__ C) {
  __shared__ alignas(16) int8_t lds[3 * SLOT];  // 48 KiB -> 3 blocks/CU
  const int tid = threadIdx.x;
  const int wave = tid >> 6;   // 0..3
  const int lane = tid & 63;

  // XCD slab swizzle: 4096 blocks, 64x64 tiles of 128; xcd=b&7 -> rows [8x,8x+8), col-major
  const int b = blockIdx.x;
  const int tr = (b & 7) * 8 + ((b >> 3) & 7);
  const int tc = b >> 6;
  const int brow = tr * 128;
  const int bcol = tc * 128;

  // staging: 8 chunks of 1KB per matrix (16 rows x 64B); wave stages chunks {2w, 2w+1}.
  const int rA0 = (wave * 2 + 0) * 16 + (lane >> 2);
  const int rA1 = (wave * 2 + 1) * 16 + (lane >> 2);
  const int c16 = lane & 3;
  const int cA0 = ((c16 ^ ((rA0 >> 1) & 3)) << 4);
  const int cA1 = ((c16 ^ ((rA1 >> 1) & 3)) << 4);
  const int8_t* gA0 = A + (size_t)(brow + rA0) * K_DIM + cA0;
  const int8_t* gA1 = A + (size_t)(brow + rA1) * K_DIM + cA1;
  const int8_t* gB0 = B + (size_t)(bcol + rA0) * K_DIM + cA0;
  const int8_t* gB1 = B + (size_t)(bcol + rA1) * K_DIM + cA1;
  const int dA0 = (wave * 2 + 0) * 1024;          // slot-relative LDS dests (wave-uniform)
  const int dA1 = (wave * 2 + 1) * 1024;
  const int dB0 = 8192 + (wave * 2 + 0) * 1024;
  const int dB1 = 8192 + (wave * 2 + 1) * 1024;

  // fragment read offsets (swizzled), slot-relative
  const int wr = wave >> 1, wc = wave & 1;
  int aoff[4], boff[4];
#pragma unroll
  for (int i = 0; i < 4; i++) {
    int lr = wr * 64 + i * 16 + (lane & 15);
    aoff[i] = lr * 64 + ((((lane >> 4) ^ ((lr >> 1) & 3))) << 4);
    int lc = wc * 64 + i * 16 + (lane & 15);
    boff[i] = 8192 + lc * 64 + ((((lane >> 4) ^ ((lc >> 1) & 3))) << 4);
  }

  v4i acc[4][4];
  const v4i vzero = {0, 0, 0, 0};
#pragma unroll
  for (int i = 0; i < 4; i++)
#pragma unroll
    for (int j = 0; j < 4; j++) acc[i][j] = vzero;

  // prologue: stage tile 0 -> slot 0, tile 1 -> slot 1 (4 loads/wave each)
  ASYNC16(gA0, lds + dA0);
  ASYNC16(gA1, lds + dA1);
  ASYNC16(gB0, lds + dB0);
  ASYNC16(gB1, lds + dB1);
  ASYNC16(gA0 + 64, lds + SLOT + dA0);
  ASYNC16(gA1 + 64, lds + SLOT + dA1);
  ASYNC16(gB0 + 64, lds + SLOT + dB0);
  ASYNC16(gB1 + 64, lds + SLOT + dB1);

  int rbase = 0;         // read slot base
  int sbase = 2 * SLOT;  // stage slot base
  for (int t = 0; t < 32; ++t) {
    // tile t landed (its 4 per-wave loads are the oldest outstanding)
    if (t < 31) asm volatile("s_waitcnt vmcnt(4)" ::: "memory");
    else        asm volatile("s_waitcnt vmcnt(0)" ::: "memory");
    __builtin_amdgcn_s_barrier();
    // stage tile t+2 into slot(t+2)%3 (lands >= 1 full K-step later)
    if (t < 30) {
      const int kt = (t + 2) * 64;
      ASYNC16(gA0 + kt, lds + sbase + dA0);
      ASYNC16(gA1 + kt, lds + sbase + dA1);
      ASYNC16(gB0 + kt, lds + sbase + dB0);
      ASYNC16(gB1 + kt, lds + sbase + dB1);
    }
    v4i af[4], bf[4];
#pragma unroll
    for (int i = 0; i < 4; i++) af[i] = *(const v4i*)(lds + rbase + aoff[i]);
#pragma unroll
    for (int j = 0; j < 4; j++) bf[j] = *(const v4i*)(lds + rbase + boff[j]);
    __builtin_amdgcn_s_setprio(1);
#pragma unroll
    for (int i = 0; i < 4; i++)
#pragma unroll
      for (int j = 0; j < 4; j++)
        acc[i][j] = __builtin_amdgcn_mfma_i32_16x16x64_i8(af[i], bf[j], acc[i][j], 0, 0, 0);
    __builtin_amdgcn_s_setprio(0);
    rbase = (rbase == 2 * SLOT) ? 0 : rbase + SLOT;
    sbase = (sbase == 2 * SLOT) ? 0 : sbase + SLOT;
  }

  // double accumulators (midpoint = odd integer), then apply risky corrections
#pragma unroll
  for (int i = 0; i < 4; i++)
#pragma unroll
    for (int j = 0; j < 4; j++) acc[i][j] = acc[i][j] + acc[i][j];

  const int crow0 = brow + wr * 64;
  const int ccol0 = bcol + wc * 64;

#define CORR(J)                                                                \
  {                                                                            \
    _Pragma("unroll") for (int i = 0; i < 4; i++) {                            \
      _Pragma("unroll") for (int r = 0; r < 4; r++) {                          \
        int grow = crow0 + i * 16 + ((lane >> 4) << 2) + r;                    \
        int xv = (int)A[(size_t)grow * K_DIM + k];                             \
        acc[i][J][r] += sv * xv;                                               \
      }                                                                        \
    }                                                                          \
  }

  {
    int bkt = bcol >> 7;
    int cnt = counts[bkt];
    if (cnt > BUCKET_CAP) cnt = BUCKET_CAP;
    const int* bk = buckets + bkt * BUCKET_CAP;
    for (int e = 0; e < cnt; ++e) {
      int word = bk[e];
      int k = word & 2047;
      int n = (word >> 11) & 8191;
      int sv = ((word >> 24) & 1) ? -1 : 1;
      int lc = n - bcol;  // in [0,128)
      if (((lc >> 6) & 1) == wc && (lc & 15) == (lane & 15)) {
        int j = (lc >> 4) & 3;
        switch (j) {
          case 0: CORR(0); break;
          case 1: CORR(1); break;
          case 2: CORR(2); break;
          case 3: CORR(3); break;
        }
      }
    }
  }
#undef CORR

  // epilogue: C[m][n] = (2*acc_corrected) * (scale_m/2) + bias[n]  (normal cached stores)
#pragma unroll
  for (int i = 0; i < 4; i++) {
#pragma unroll
    for (int r = 0; r < 4; r++) {
      int grow = crow0 + i * 16 + ((lane >> 4) << 2) + r;
      float sc = scales[grow] * 0.5f;
      float* crow = C + (size_t)grow * N_DIM;
#pragma unroll
      for (int j = 0; j < 4; j++) {
        int gcol = ccol0 + j * 16 + (lane & 15);
        crow[gcol] = (float)acc[i][j][r] * sc + bias[gcol];
      }
    }
  }
}

extern "C" void kernel_launch(void* const* d_in, const int* in_sizes, int n_in,
                              void* d_out, int out_size, void* d_ws, size_t ws_size,
                              hipStream_t stream) {
  const float* x = (const float*)d_in[0];
  const float* w = (const float*)d_in[1];
  const float* bias = (const float*)d_in[2];
  float* out = (float*)d_out;

  char* ws = (char*)d_ws;
  float* s1 = (float*)(ws);                          // 512 KiB
  float* s2 = (float*)(ws + 0x100000);               // 16 KiB
  float* gamma_f = (float*)(ws + 0x110000);          // 4 B
  float* scales = (float*)(ws + 0x120000);           // 32 KiB
  int* counts = (int*)(ws + 0x130000);               // 64 * 4 B
  int* buckets = (int*)(ws + 0x131000);              // 256 KiB
  int8_t* Aq = (int8_t*)(ws + 0x200000);                             // 16 MiB
  int8_t* Wq = (int8_t*)(ws + 0x200000 + (size_t)M_DIM * K_DIM);     // 16 MiB

  abssum_stage1<<<512, 256, 0, stream>>>(w, s1);
  abssum_stage2<<<16, 256, 0, stream>>>(s1, s2);
  gamma_stage3<<<1, 256, 0, stream>>>(s2, gamma_f, counts);
  wq_kernel<<<(N_DIM * K_DIM / 4 + 255) / 256, 256, 0, stream>>>(
      (const float4*)w, gamma_f, (int*)Wq, counts, buckets);
  lnq_kernel<<<M_DIM, 256, 0, stream>>>(x, gamma_f, Aq, scales);
  gemm_i8_kernel<<<4096, 256, 0, stream>>>(Aq, Wq, scales, bias, counts, buckets, out);
}

// Round 17
// 291.958 us; speedup vs baseline: 1.5607x; 1.0584x over previous
//
#include <hip/hip_runtime.h>
#include <stdint.h>

typedef int v4i __attribute__((ext_vector_type(4)));

#define M_DIM 8192   // B*S = 2*4096
#define N_DIM 8192   // OUT
#define K_DIM 2048   // IN
#define RISKY_TAU 1e-4f
#define BUCKET_CAP 1024
#define SLOT 32768   // LDS slot: A[256][64] 16KB + B[256][64] 16KB

// async global->LDS, 16B per lane (dest = wave-uniform base + lane*16)
#define ASYNC16(g, l) __builtin_amdgcn_global_load_lds(                        \
    (const __attribute__((address_space(1))) void*)(uintptr_t)(g),             \
    (__attribute__((address_space(3))) void*)(uint32_t)(uintptr_t)(l), 16, 0, 0)

// ---------------- 1) numpy-pairwise f32 sum of |w| ----------------
__global__ __launch_bounds__(256) void abssum_stage1(const float* __restrict__ w,
                                                     float* __restrict__ s1) {
  int b = blockIdx.x * 256 + threadIdx.x;  // 131072 leaf blocks of 128
  const float* p = w + (size_t)b * 128;
  float r[8];
#pragma unroll
  for (int j = 0; j < 8; j++) r[j] = fabsf(p[j]);
  for (int i = 8; i < 128; i += 8) {
#pragma unroll
    for (int j = 0; j < 8; j++) r[j] += fabsf(p[i + j]);
  }
  s1[b] = ((r[0] + r[1]) + (r[2] + r[3])) + ((r[4] + r[5]) + (r[6] + r[7]));
}

// fused stage2+stage3: thread t computes s2[t*16+i] (i=0..15) with the identical
// 32-leaf adjacent-pairing tree, then the identical 16-way + 256-way trees.
__global__ __launch_bounds__(256) void gamma_fused(const float* __restrict__ s1,
                                                   float* __restrict__ gp,
                                                   int* __restrict__ counts) {
  int t = threadIdx.x;
  if (t < 64) counts[t] = 0;  // fold zero_counts in
  float v[16];
#pragma unroll
  for (int i = 0; i < 16; i++) {
    const float* p = s1 + (size_t)(t * 16 + i) * 32;
    float u[32];
#pragma unroll
    for (int j = 0; j < 32; j++) u[j] = p[j];
#pragma unroll
    for (int s = 1; s < 32; s *= 2) {
#pragma unroll
      for (int j = 0; j < 32; j += 2 * s) u[j] += u[j + s];
    }
    v[i] = u[0];
  }
#pragma unroll
  for (int s = 1; s < 16; s *= 2) {
#pragma unroll
    for (int i = 0; i < 16; i += 2 * s) v[i] += v[i + s];
  }
  __shared__ float sm[256];
  sm[t] = v[0];
  for (int s = 1; s < 256; s *= 2) {
    __syncthreads();
    if ((t & (2 * s - 1)) == 0) sm[t] += sm[t + s];
  }
  __syncthreads();
  if (t == 0) {
    float g = sm[0] * 0x1p-24f;  // /(8192*2048), exact pow2 scale
    gp[0] = fmaxf(g, 1e-5f);
  }
}

// ---------------- 2) ternary weight quant + risky-midpoint detection ----------------
__global__ __launch_bounds__(256) void wq_kernel(const float4* __restrict__ w4,
                                                 const float* __restrict__ gp,
                                                 int* __restrict__ wq,
                                                 int* __restrict__ counts,
                                                 int* __restrict__ buckets) {
  int i = blockIdx.x * 256 + threadIdx.x;
  float g = gp[0];
  float4 v = w4[i];
  float e[4] = {v.x, v.y, v.z, v.w};
  int q[4];
#pragma unroll
  for (int c = 0; c < 4; c++) {
    q[c] = (int)rintf(fminf(fmaxf(e[c] / g, -1.0f), 1.0f));
    float t = fabsf(e[c]) / g;
    if (fabsf(t - 0.5f) < RISKY_TAU) {
      int flat = i * 4 + c;
      int n = flat >> 11;          // weight row (output col)
      int k = flat & 2047;
      int sgn_neg = (e[c] < 0.0f) ? 1 : 0;
      int sbit = (q[c] == 0) ? sgn_neg : (1 - sgn_neg);
      int b = n >> 7;
      int idx = atomicAdd(&counts[b], 1);
      if (idx < BUCKET_CAP)
        buckets[b * BUCKET_CAP + idx] = k | (n << 11) | (sbit << 24);
    }
  }
  wq[i] = (q[0] & 0xFF) | ((q[1] & 0xFF) << 8) | ((q[2] & 0xFF) << 16) | ((q[3] & 0xFF) << 24);
}

// ---------------- 3) fused LayerNorm + absmax int8 quant (shuffle reductions) ----------
__global__ __launch_bounds__(256) void lnq_kernel(const float* __restrict__ x,
                                                  const float* __restrict__ gp,
                                                  int8_t* __restrict__ xq,
                                                  float* __restrict__ scales) {
  const int row = blockIdx.x;
  const int t = threadIdx.x;
  const int wv = t >> 6;
  const float4* xr = (const float4*)(x + (size_t)row * K_DIM);
  float4 a = xr[t];
  float4 b = xr[t + 256];
  double v[8] = {a.x, a.y, a.z, a.w, b.x, b.y, b.z, b.w};
  double s = 0.0, ss = 0.0;
#pragma unroll
  for (int i = 0; i < 8; i++) { s += v[i]; ss += v[i] * v[i]; }
  // wave-level f64 butterfly reduce
#pragma unroll
  for (int off = 32; off > 0; off >>= 1) {
    s += __shfl_xor(s, off);
    ss += __shfl_xor(ss, off);
  }
  __shared__ double smA[4], smB[4], smM[4];
  if ((t & 63) == 0) { smA[wv] = s; smB[wv] = ss; }
  __syncthreads();
  double sT = (smA[0] + smA[1]) + (smA[2] + smA[3]);
  double ssT = (smB[0] + smB[1]) + (smB[2] + smB[3]);
  double mu = sT * (1.0 / 2048.0);
  double var = ssT * (1.0 / 2048.0) - mu * mu;  // biased variance
  double inv = 1.0 / sqrt(var + 1e-5);
  double mx = 0.0;
#pragma unroll
  for (int i = 0; i < 8; i++) {
    v[i] = (v[i] - mu) * inv;
    double av = fabs(v[i]);
    if (av > mx) mx = av;
  }
#pragma unroll
  for (int off = 32; off > 0; off >>= 1) {
    double o = __shfl_xor(mx, off);
    if (o > mx) mx = o;
  }
  if ((t & 63) == 0) smM[wv] = mx;
  __syncthreads();
  double eta = fmax(fmax(fmax(smM[0], smM[1]), fmax(smM[2], smM[3])), 1e-5);
  double r = 127.0 / eta;
  int q[8];
#pragma unroll
  for (int i = 0; i < 8; i++) {
    double qq = rint(v[i] * r);  // round-half-even, then clip
    qq = fmin(fmax(qq, -128.0), 127.0);
    q[i] = (int)qq;
  }
  int p0 = (q[0] & 0xFF) | ((q[1] & 0xFF) << 8) | ((q[2] & 0xFF) << 16) | ((q[3] & 0xFF) << 24);
  int p1 = (q[4] & 0xFF) | ((q[5] & 0xFF) << 8) | ((q[6] & 0xFF) << 16) | ((q[7] & 0xFF) << 24);
  int* orow = (int*)(xq + (size_t)row * K_DIM);
  orow[t] = p0;
  orow[t + 256] = p1;
  if (t == 0) scales[row] = (float)((double)gp[0] * eta * (1.0 / 127.0));
}

// ---------------- 4) int8 MFMA GEMM: r12 restored verbatim (best: 233us) ----------------
// 256x256, 8 waves, ring-3 LDS (96KB), counted vmcnt(4) (never 0 in-loop), raw s_barrier,
// XCD slab swizzle (FETCH 118MB), (r>>1)&3 LDS swizzle (0 conflicts).
__global__ __launch_bounds__(512) void gemm_i8_kernel(const int8_t* __restrict__ A,
                                                      const int8_t* __restrict__ B,
                                                      const float* __restrict__ scales,
                                                      const float* __restrict__ bias,
                                                      const int* __restrict__ counts,
                                                      const int* __restrict__ buckets,
                                                      float* __restrict__ C) {
  __shared__ alignas(16) int8_t lds[3 * SLOT];  // 96 KiB
  const int tid = threadIdx.x;
  const int wave = tid >> 6;   // 0..7
  const int lane = tid & 63;

  // XCD slab swizzle: 1024 blocks, xcd = b&7 owns tile rows [4*xcd, 4*xcd+4), col-major
  const int b = blockIdx.x;
  const int tr = (b & 7) * 4 + ((b >> 3) & 3);
  const int tc = b >> 5;
  const int brow = tr * 256;
  const int bcol = tc * 256;

  // staging: per matrix 16 chunks of 1KB (16 rows x 64B); wave w stages chunks {2w,2w+1}.
  const int chunkr = lane >> 2;
  const int sl = lane & 3;
  const int8_t* gA[2];
  const int8_t* gB[2];
  int dA[2], dB[2];
#pragma unroll
  for (int c = 0; c < 2; c++) {
    int ch = wave * 2 + c;
    int r = ch * 16 + chunkr;
    int scol = ((sl ^ ((r >> 1) & 3)) << 4);
    gA[c] = A + (size_t)(brow + r) * K_DIM + scol;
    gB[c] = B + (size_t)(bcol + r) * K_DIM + scol;
    dA[c] = ch * 1024;           // wave-uniform LDS base (+lane*16 by HW)
    dB[c] = 16384 + ch * 1024;
  }

  // fragment read offsets (swizzled), slot-relative
  const int wr = wave >> 2;    // 0..1  (M half)
  const int wc = wave & 3;     // 0..3  (N quarter)
  const int ks = lane >> 4;    // k-slot 0..3
  int aoff[8], boff[4];
#pragma unroll
  for (int m = 0; m < 8; m++) {
    int r = wr * 128 + m * 16 + (lane & 15);
    aoff[m] = r * 64 + ((ks ^ ((r >> 1) & 3)) << 4);
  }
#pragma unroll
  for (int n = 0; n < 4; n++) {
    int r = wc * 64 + n * 16 + (lane & 15);
    boff[n] = 16384 + r * 64 + ((ks ^ ((r >> 1) & 3)) << 4);
  }

  v4i acc[8][4];
  const v4i vzero = {0, 0, 0, 0};
#pragma unroll
  for (int m = 0; m < 8; m++)
#pragma unroll
    for (int n = 0; n < 4; n++) acc[m][n] = vzero;

  // prologue: stage tile 0 -> slot 0, tile 1 -> slot 1 (4 loads/wave each)
#pragma unroll
  for (int c = 0; c < 2; c++) {
    ASYNC16(gA[c], lds + dA[c]);
    ASYNC16(gB[c], lds + dB[c]);
  }
#pragma unroll
  for (int c = 0; c < 2; c++) {
    ASYNC16(gA[c] + 64, lds + SLOT + dA[c]);
    ASYNC16(gB[c] + 64, lds + SLOT + dB[c]);
  }

  int rbase = 0;         // read slot base
  int sbase = 2 * SLOT;  // stage slot base
  for (int t = 0; t < 32; ++t) {
    // tile t landed (its 4 per-wave loads are the oldest outstanding)
    if (t < 31) asm volatile("s_waitcnt vmcnt(4)" ::: "memory");
    else        asm volatile("s_waitcnt vmcnt(0)" ::: "memory");
    __builtin_amdgcn_s_barrier();
    // stage tile t+2 into slot(t+2)%3 (lands >= 1 full K-step later)
    if (t < 30) {
      const int kt = (t + 2) * 64;
#pragma unroll
      for (int c = 0; c < 2; c++) {
        ASYNC16(gA[c] + kt, lds + sbase + dA[c]);
        ASYNC16(gB[c] + kt, lds + sbase + dB[c]);
      }
    }
    v4i bf[4], af[8];
#pragma unroll
    for (int n = 0; n < 4; n++) bf[n] = *(const v4i*)(lds + rbase + boff[n]);
#pragma unroll
    for (int m = 0; m < 8; m++) af[m] = *(const v4i*)(lds + rbase + aoff[m]);
    __builtin_amdgcn_s_setprio(1);
#pragma unroll
    for (int m = 0; m < 8; m++)
#pragma unroll
      for (int n = 0; n < 4; n++)
        acc[m][n] = __builtin_amdgcn_mfma_i32_16x16x64_i8(af[m], bf[n], acc[m][n], 0, 0, 0);
    __builtin_amdgcn_s_setprio(0);
    rbase = (rbase == 2 * SLOT) ? 0 : rbase + SLOT;
    sbase = (sbase == 2 * SLOT) ? 0 : sbase + SLOT;
  }

  // double accumulators (midpoint = odd integer), then apply risky corrections
#pragma unroll
  for (int m = 0; m < 8; m++)
#pragma unroll
    for (int n = 0; n < 4; n++) acc[m][n] = acc[m][n] + acc[m][n];

  const int crow0 = brow + wr * 128;
  const int ccol0 = bcol + wc * 64;

#define CORR(J)                                                                \
  {                                                                            \
    _Pragma("unroll") for (int m = 0; m < 8; m++) {                            \
      _Pragma("unroll") for (int r = 0; r < 4; r++) {                          \
        int grow = crow0 + m * 16 + ((lane >> 4) << 2) + r;                    \
        int xv = (int)A[(size_t)grow * K_DIM + k];                             \
        acc[m][J][r] += sv * xv;                                               \
      }                                                                        \
    }                                                                          \
  }

  {
    int bkt = (bcol + wc * 64) >> 7;  // 128-col bucket containing this wave's 64 cols
    int cnt = counts[bkt];
    if (cnt > BUCKET_CAP) cnt = BUCKET_CAP;
    const int* bk = buckets + bkt * BUCKET_CAP;
    for (int e = 0; e < cnt; ++e) {
      int word = bk[e];
      int k = word & 2047;
      int nc = (word >> 11) & 8191;
      int sv = ((word >> 24) & 1) ? -1 : 1;
      if (((nc >> 6) & 1) == (wc & 1) && (nc & 15) == (lane & 15)) {
        int j = (nc >> 4) & 3;
        switch (j) {
          case 0: CORR(0); break;
          case 1: CORR(1); break;
          case 2: CORR(2); break;
          case 3: CORR(3); break;
        }
      }
    }
  }
#undef CORR

  // epilogue: C[m][n] = (2*acc_corrected) * (scale_m/2) + bias[n]  (normal cached stores)
#pragma unroll
  for (int m = 0; m < 8; m++) {
#pragma unroll
    for (int r = 0; r < 4; r++) {
      int grow = crow0 + m * 16 + ((lane >> 4) << 2) + r;
      float sc = scales[grow] * 0.5f;
      float* crow = C + (size_t)grow * N_DIM;
#pragma unroll
      for (int n = 0; n < 4; n++) {
        int gcol = ccol0 + n * 16 + (lane & 15);
        crow[gcol] = (float)acc[m][n][r] * sc + bias[gcol];
      }
    }
  }
}

extern "C" void kernel_launch(void* const* d_in, const int* in_sizes, int n_in,
                              void* d_out, int out_size, void* d_ws, size_t ws_size,
                              hipStream_t stream) {
  const float* x = (const float*)d_in[0];
  const float* w = (const float*)d_in[1];
  const float* bias = (const float*)d_in[2];
  float* out = (float*)d_out;

  char* ws = (char*)d_ws;
  float* s1 = (float*)(ws);                          // 512 KiB
  float* gamma_f = (float*)(ws + 0x110000);          // 4 B
  float* scales = (float*)(ws + 0x120000);           // 32 KiB
  int* counts = (int*)(ws + 0x130000);               // 64 * 4 B
  int* buckets = (int*)(ws + 0x131000);              // 256 KiB
  int8_t* Aq = (int8_t*)(ws + 0x200000);                             // 16 MiB
  int8_t* Wq = (int8_t*)(ws + 0x200000 + (size_t)M_DIM * K_DIM);     // 16 MiB

  abssum_stage1<<<512, 256, 0, stream>>>(w, s1);
  gamma_fused<<<1, 256, 0, stream>>>(s1, gamma_f, counts);
  wq_kernel<<<(N_DIM * K_DIM / 4 + 255) / 256, 256, 0, stream>>>(
      (const float4*)w, gamma_f, (int*)Wq, counts, buckets);
  lnq_kernel<<<M_DIM, 256, 0, stream>>>(x, gamma_f, Aq, scales);
  gemm_i8_kernel<<<1024, 512, 0, stream>>>(Aq, Wq, scales, bias, counts, buckets, out);
}